// Round 7
// baseline (443.761 us; speedup 1.0000x reference)
//
#include <hip/hip_runtime.h>
#include <math.h>

#define N_NODES 100000
#define N_EDGES 3200000
#define N_GRAPHS 512
#define D_FEAT 128
#define F_HID 32

#define RPB 128                 // rows per bucket (row >> 7)
#define NB 782                  // ceil(100000/128)
#define CAP 5120                // fixed bucket capacity (mean 4092 -> 16 sigma margin)
#define CHUNK 8192              // edges per multisplit block
#define NCHUNK ((N_EDGES + CHUNK - 1) / CHUNK)   // 391

// ---- bf16 helpers (RNE, finite values only) ----
static __device__ __forceinline__ unsigned f2bf(float f) {
    unsigned u = __float_as_uint(f);
    return (u + 0x7FFFu + ((u >> 16) & 1u)) >> 16;
}
static __device__ __forceinline__ unsigned pack_bf2(float a, float b) {
    return (f2bf(b) << 16) | f2bf(a);
}
static __device__ __forceinline__ float bf_lo(unsigned u) { return __uint_as_float(u << 16); }
static __device__ __forceinline__ float bf_hi(unsigned u) { return __uint_as_float(u & 0xFFFF0000u); }

// ---------------- GEMM1: x[N,128] @ W[128,32] -> bf16 halves hA/hB [N,16] ----------
__global__ void gemm128x32(const float* __restrict__ x, const float* __restrict__ W,
                           uint2* __restrict__ hA, uint2* __restrict__ hB, int n_nodes) {
    __shared__ float Ws[128 * 32];
    for (int i = threadIdx.x; i < 128 * 32; i += 256) Ws[i] = W[i];
    __syncthreads();
    const int fg = threadIdx.x & 7;
    const int nl = threadIdx.x >> 3;
    const int node = blockIdx.x * 32 + nl;
    if (node >= n_nodes) return;
    const float4* x4 = (const float4*)(x + (size_t)node * 128);
    const float4* Ws4 = (const float4*)Ws;
    float4 acc = make_float4(0.f, 0.f, 0.f, 0.f);
    for (int kk = 0; kk < 32; ++kk) {
        float4 xv = x4[kk];
        int k = kk * 4;
        float4 w0 = Ws4[(k + 0) * 8 + fg];
        float4 w1 = Ws4[(k + 1) * 8 + fg];
        float4 w2 = Ws4[(k + 2) * 8 + fg];
        float4 w3 = Ws4[(k + 3) * 8 + fg];
        acc.x += xv.x * w0.x + xv.y * w1.x + xv.z * w2.x + xv.w * w3.x;
        acc.y += xv.x * w0.y + xv.y * w1.y + xv.z * w2.y + xv.w * w3.y;
        acc.z += xv.x * w0.z + xv.y * w1.z + xv.z * w2.z + xv.w * w3.z;
        acc.w += xv.x * w0.w + xv.y * w1.w + xv.z * w2.w + xv.w * w3.w;
    }
    uint2 o = make_uint2(pack_bf2(acc.x, acc.y), pack_bf2(acc.z, acc.w));
    if (fg < 4) hA[(size_t)node * 4 + fg] = o;
    else        hB[(size_t)node * 4 + fg - 4] = o;
}

// ---------------- GEMM: h[N,32] (fp32) @ W[32,32] -> bf16 halves ----------------
__global__ void gemm32x32(const float* __restrict__ h, const float* __restrict__ W,
                          uint2* __restrict__ hA, uint2* __restrict__ hB, int n_nodes) {
    __shared__ float Ws[32 * 32];
    for (int i = threadIdx.x; i < 32 * 32; i += 256) Ws[i] = W[i];
    __syncthreads();
    const int fg = threadIdx.x & 7;
    const int nl = threadIdx.x >> 3;
    const int node = blockIdx.x * 32 + nl;
    if (node >= n_nodes) return;
    const float4* h4 = (const float4*)(h + (size_t)node * 32);
    const float4* Ws4 = (const float4*)Ws;
    float4 acc = make_float4(0.f, 0.f, 0.f, 0.f);
    for (int kk = 0; kk < 8; ++kk) {
        float4 hv = h4[kk];
        int k = kk * 4;
        float4 w0 = Ws4[(k + 0) * 8 + fg];
        float4 w1 = Ws4[(k + 1) * 8 + fg];
        float4 w2 = Ws4[(k + 2) * 8 + fg];
        float4 w3 = Ws4[(k + 3) * 8 + fg];
        acc.x += hv.x * w0.x + hv.y * w1.x + hv.z * w2.x + hv.w * w3.x;
        acc.y += hv.x * w0.y + hv.y * w1.y + hv.z * w2.y + hv.w * w3.y;
        acc.z += hv.x * w0.z + hv.y * w1.z + hv.z * w2.z + hv.w * w3.z;
        acc.w += hv.x * w0.w + hv.y * w1.w + hv.z * w2.w + hv.w * w3.w;
    }
    uint2 o = make_uint2(pack_bf2(acc.x, acc.y), pack_bf2(acc.z, acc.w));
    if (fg < 4) hA[(size_t)node * 4 + fg] = o;
    else        hB[(size_t)node * 4 + fg - 4] = o;
}

// ================= stage 0: cursor init (fixed-capacity buckets) =================
__global__ void init_cursor(int* __restrict__ cursor) {
    int t = blockIdx.x * blockDim.x + threadIdx.x;
    if (t < NB) cursor[t] = t * CAP;
}

// ================= stage 1: bucket multisplit, 1024 threads, LDS-staged ==========
__global__ __launch_bounds__(1024) void bucket_scatter(
        const int* __restrict__ row, const int* __restrict__ col,
        const float* __restrict__ w, int* __restrict__ cursor,
        uint2* __restrict__ rec, int n_edges) {
    __shared__ uint2 srt[CHUNK];      // 64 KB
    __shared__ int hist[NB];
    __shared__ int lofs[NB + 1];
    __shared__ int lbase[NB];
    __shared__ int tsum[1024];
    const int t = threadIdx.x;
    const int base = blockIdx.x * CHUNK;
    const int count = min(CHUNK, n_edges - base);

    if (t < NB) hist[t] = 0;
    __syncthreads();
    int rloc[CHUNK / 1024];           // cache row[] between passes
    #pragma unroll
    for (int j = 0; j < CHUNK / 1024; ++j) {
        int i = t + j * 1024;
        int r = -1;
        if (i < count) { r = row[base + i]; atomicAdd(&hist[r >> 7], 1); }
        rloc[j] = r;
    }
    __syncthreads();
    int v = (t < NB) ? hist[t] : 0;
    tsum[t] = v;
    __syncthreads();
    for (int off = 1; off < 1024; off <<= 1) {
        int add = (t >= off) ? tsum[t - off] : 0;
        __syncthreads();
        tsum[t] += add;
        __syncthreads();
    }
    if (t < NB) lofs[t] = tsum[t] - v;
    if (t == 1023) lofs[NB] = tsum[1023];
    __syncthreads();
    if (t < NB) {
        lbase[t] = v ? atomicAdd(&cursor[t], v) : 0;
        hist[t] = 0;
    }
    __syncthreads();
    #pragma unroll
    for (int j = 0; j < CHUNK / 1024; ++j) {
        int i = t + j * 1024;
        if (i < count) {
            int e = base + i;
            int r = rloc[j];
            int b = r >> 7;
            int pos = lofs[b] + atomicAdd(&hist[b], 1);
            srt[pos] = make_uint2(((unsigned)(r & 127) << 17) | (unsigned)col[e],
                                  __float_as_uint(w[e]));
        }
    }
    __syncthreads();
    // coalesced write-out (runs of ~10 consecutive rec addresses)
    for (int i = t; i < count; i += 1024) {
        uint2 vv = srt[i];
        int lo = 0, hi = NB;
        while (hi - lo > 1) {
            int mid = (lo + hi) >> 1;
            if (lofs[mid] <= i) lo = mid; else hi = mid;
        }
        rec[lbase[lo] + (i - lofs[lo])] = vv;
    }
}

// ================= stage 2: compact-base scan over bucket counts =================
__global__ void scan_nb(const int* __restrict__ cursor, int* __restrict__ bbase) {
    __shared__ int s[1024];
    const int t = threadIdx.x;
    int v = (t < NB) ? (cursor[t] - t * CAP) : 0;
    s[t] = v;
    __syncthreads();
    for (int off = 1; off < 1024; off <<= 1) {
        int add = (t >= off) ? s[t - off] : 0;
        __syncthreads();
        s[t] += add;
        __syncthreads();
    }
    if (t < NB) bbase[t] = s[t] - v;
    if (t == NB - 1) bbase[NB] = s[t];
}

// ====== stage 3: per-bucket counting sort -> compact CSR, 4 B records ======
// rec2[i] = (w_bf16_no_sign:15) << 17 | col:17
__global__ __launch_bounds__(512) void bucket_sort(
        const int* __restrict__ cursor, const int* __restrict__ bbase,
        const uint2* __restrict__ rec, unsigned* __restrict__ rec2,
        int* __restrict__ row_ptr, int n_nodes) {
    __shared__ unsigned srt[CAP];     // 20 KB
    __shared__ int hist[RPB];
    __shared__ int lofs[RPB];
    const int t = threadIdx.x;
    const int b = blockIdx.x;
    const int sbase = b * CAP;
    const int cnt = cursor[b] - sbase;
    const int gbase = bbase[b];

    if (t < RPB) hist[t] = 0;
    __syncthreads();
    for (int i = t; i < cnt; i += 512)
        atomicAdd(&hist[rec[sbase + i].x >> 17], 1);
    __syncthreads();
    if (t < RPB) lofs[t] = hist[t];
    __syncthreads();
    for (int off = 1; off < RPB; off <<= 1) {
        int v = (t < RPB && t >= off) ? lofs[t - off] : 0;
        __syncthreads();
        if (t < RPB) lofs[t] += v;
        __syncthreads();
    }
    if (t < RPB) {
        int excl = lofs[t] - hist[t];
        int gr = b * RPB + t;
        if (gr <= n_nodes) row_ptr[gr] = gbase + excl;
        hist[t] = excl;               // reuse as placement cursor
    }
    __syncthreads();
    for (int i = t; i < cnt; i += 512) {
        uint2 v = rec[sbase + i];
        int pos = atomicAdd(&hist[v.x >> 17], 1);
        unsigned wb = f2bf(__uint_as_float(v.y)) & 0x7FFFu;   // w > 0: drop sign
        srt[pos] = (wb << 17) | (v.x & 0x1FFFFu);
    }
    __syncthreads();
    for (int i = t; i < cnt; i += 512)
        rec2[gbase + i] = srt[i];
}

// ====== SPMM half: gather bf16 [N,16] (3.2 MB, L2-resident) + bias + ELU ======
// 4 lanes per node (one uint2 = 4 bf16 feats each); 64 nodes / 256-block.
__global__ void spmm_half(const int* __restrict__ rp, const unsigned* __restrict__ rec2,
                          const uint2* __restrict__ hh, const float* __restrict__ b,
                          float* __restrict__ out, int half, int n_nodes) {
    const int fl = threadIdx.x & 3;
    const int node = blockIdx.x * 64 + (threadIdx.x >> 2);
    if (node >= n_nodes) return;
    const int s = rp[node], e = rp[node + 1];
    float4 acc = make_float4(0.f, 0.f, 0.f, 0.f);
    int i = s;
    for (; i + 4 <= e; i += 4) {
        unsigned p0 = rec2[i];
        unsigned p1 = rec2[i + 1];
        unsigned p2 = rec2[i + 2];
        unsigned p3 = rec2[i + 3];
        uint2 g0 = hh[(size_t)(p0 & 0x1FFFF) * 4 + fl];
        uint2 g1 = hh[(size_t)(p1 & 0x1FFFF) * 4 + fl];
        uint2 g2 = hh[(size_t)(p2 & 0x1FFFF) * 4 + fl];
        uint2 g3 = hh[(size_t)(p3 & 0x1FFFF) * 4 + fl];
        float w0 = __uint_as_float((p0 >> 17) << 16);
        float w1 = __uint_as_float((p1 >> 17) << 16);
        float w2 = __uint_as_float((p2 >> 17) << 16);
        float w3 = __uint_as_float((p3 >> 17) << 16);
        acc.x += w0 * bf_lo(g0.x) + w1 * bf_lo(g1.x) + w2 * bf_lo(g2.x) + w3 * bf_lo(g3.x);
        acc.y += w0 * bf_hi(g0.x) + w1 * bf_hi(g1.x) + w2 * bf_hi(g2.x) + w3 * bf_hi(g3.x);
        acc.z += w0 * bf_lo(g0.y) + w1 * bf_lo(g1.y) + w2 * bf_lo(g2.y) + w3 * bf_lo(g3.y);
        acc.w += w0 * bf_hi(g0.y) + w1 * bf_hi(g1.y) + w2 * bf_hi(g2.y) + w3 * bf_hi(g3.y);
    }
    for (; i < e; ++i) {
        unsigned p0 = rec2[i];
        uint2 g0 = hh[(size_t)(p0 & 0x1FFFF) * 4 + fl];
        float w0 = __uint_as_float((p0 >> 17) << 16);
        acc.x += w0 * bf_lo(g0.x); acc.y += w0 * bf_hi(g0.x);
        acc.z += w0 * bf_lo(g0.y); acc.w += w0 * bf_hi(g0.y);
    }
    float4 bv = ((const float4*)b)[half * 4 + fl];
    acc.x += bv.x; acc.y += bv.y; acc.z += bv.z; acc.w += bv.w;
    acc.x = acc.x > 0.f ? acc.x : (expf(acc.x) - 1.f);
    acc.y = acc.y > 0.f ? acc.y : (expf(acc.y) - 1.f);
    acc.z = acc.z > 0.f ? acc.z : (expf(acc.z) - 1.f);
    acc.w = acc.w > 0.f ? acc.w : (expf(acc.w) - 1.f);
    ((float4*)(out + (size_t)node * 32 + half * 16))[fl] = acc;
}

// ================= pool: sorted seg run-accumulation =================
__global__ void pool_seg(const float* __restrict__ h, const int* __restrict__ seg,
                         float* __restrict__ g, int n_nodes) {
    const int t = threadIdx.x;
    const int f = t & 31;
    const int sub = t >> 5;
    const int base = blockIdx.x * 512;
    float run = 0.f;
    int cur = -1;
    for (int i = 0; i < 64; ++i) {
        int node = base + sub + i * 8;
        if (node >= n_nodes) break;
        int sg = seg[node];
        if (sg != cur) {
            if (cur >= 0) atomicAdd(&g[(size_t)cur * 32 + f], run);
            cur = sg;
            run = 0.f;
        }
        run += h[(size_t)node * 32 + f];
    }
    if (cur >= 0) atomicAdd(&g[(size_t)cur * 32 + f], run);
}

// ================= MLP head =================
__global__ void head_mlp(const float* __restrict__ g,
                         const float* __restrict__ Wd1, const float* __restrict__ bd1,
                         const float* __restrict__ Wd2, const float* __restrict__ bd2,
                         const float* __restrict__ Wd3, const float* __restrict__ bd3,
                         float* __restrict__ out) {
    __shared__ float gr[32];
    __shared__ float s1[64];
    __shared__ float s2[32];
    const int gid = blockIdx.x;
    const int t = threadIdx.x;
    if (t < 32) gr[t] = g[(size_t)gid * 32 + t];
    __syncthreads();
    float a = bd1[t];
    for (int k = 0; k < 32; ++k) a += gr[k] * Wd1[k * 64 + t];
    s1[t] = fmaxf(a, 0.f);
    __syncthreads();
    if (t < 32) {
        float a2 = bd2[t];
        for (int k = 0; k < 64; ++k) a2 += s1[k] * Wd2[k * 32 + t];
        s2[t] = fmaxf(a2, 0.f);
    }
    __syncthreads();
    if (t == 0) {
        float a3 = bd3[0];
        for (int k = 0; k < 32; ++k) a3 += s2[k] * Wd3[k];
        out[gid] = 1.f / (1.f + expf(-a3));
    }
}

extern "C" void kernel_launch(void* const* d_in, const int* in_sizes, int n_in,
                              void* d_out, int out_size, void* d_ws, size_t ws_size,
                              hipStream_t stream) {
    const float* x   = (const float*)d_in[0];
    const int*   ei  = (const int*)d_in[1];
    const float* ew  = (const float*)d_in[2];
    const int*   seg = (const int*)d_in[3];
    const float* W1  = (const float*)d_in[4];
    const float* b1  = (const float*)d_in[5];
    const float* W2  = (const float*)d_in[6];
    const float* b2  = (const float*)d_in[7];
    const float* W3  = (const float*)d_in[8];
    const float* b3  = (const float*)d_in[9];
    const float* Wd1 = (const float*)d_in[10];
    const float* bd1 = (const float*)d_in[11];
    const float* Wd2 = (const float*)d_in[12];
    const float* bd2 = (const float*)d_in[13];
    const float* Wd3 = (const float*)d_in[14];
    const float* bd3 = (const float*)d_in[15];
    float* out = (float*)d_out;

    const int* rowp = ei;
    const int* colp = ei + N_EDGES;

    const size_t NF  = (size_t)N_NODES * F_HID;
    const size_t NH  = (size_t)N_NODES * 16;
    const size_t REC_BYTES = (size_t)NB * CAP * sizeof(uint2);  // 32.03 MB

    // region A: rec (32 MB) during build; hA+hB (3.2+3.2 MB bf16) + B2 (12.8 MB fp32)
    // overlay it during the layer phase (19.2 MB < 32 MB).
    char*  wsb     = (char*)d_ws;
    uint2* rec     = (uint2*)wsb;
    uint2* hA      = (uint2*)wsb;                           // bf16 [N,16]
    uint2* hB      = (uint2*)(wsb + NH * 2);                // bf16 [N,16]
    float* B2      = (float*)(wsb + NH * 4);                // fp32 [N,32]
    unsigned* rec2 = (unsigned*)(wsb + REC_BYTES);          // [E] 4 B records
    int*   cursor  = (int*)(rec2 + N_EDGES);                // [NB]
    int*   bbase   = cursor + NB;                           // [NB+1]
    int*   row_ptr = bbase + NB + 1;                        // [N+1]
    float* G       = (float*)(row_ptr + N_NODES + 1);       // [512,32]

    const int gemm_grid = (N_NODES + 31) / 32;
    const int spmm_grid = (N_NODES + 63) / 64;
    const int pool_grid = (N_NODES + 511) / 512;

    // ---- CSR build (once per call) ----
    init_cursor<<<(NB + 255) / 256, 256, 0, stream>>>(cursor);
    bucket_scatter<<<NCHUNK, 1024, 0, stream>>>(rowp, colp, ew, cursor, rec, N_EDGES);
    scan_nb<<<1, 1024, 0, stream>>>(cursor, bbase);
    bucket_sort<<<NB, 512, 0, stream>>>(cursor, bbase, rec, rec2, row_ptr, N_NODES);

    // ---- layer 1 ----
    gemm128x32<<<gemm_grid, 256, 0, stream>>>(x, W1, hA, hB, N_NODES);
    spmm_half<<<spmm_grid, 256, 0, stream>>>(row_ptr, rec2, hA, b1, B2, 0, N_NODES);
    spmm_half<<<spmm_grid, 256, 0, stream>>>(row_ptr, rec2, hB, b1, B2, 1, N_NODES);

    // ---- layer 2 ----
    gemm32x32<<<gemm_grid, 256, 0, stream>>>(B2, W2, hA, hB, N_NODES);
    spmm_half<<<spmm_grid, 256, 0, stream>>>(row_ptr, rec2, hA, b2, B2, 0, N_NODES);
    spmm_half<<<spmm_grid, 256, 0, stream>>>(row_ptr, rec2, hB, b2, B2, 1, N_NODES);

    // ---- layer 3 ----
    gemm32x32<<<gemm_grid, 256, 0, stream>>>(B2, W3, hA, hB, N_NODES);
    spmm_half<<<spmm_grid, 256, 0, stream>>>(row_ptr, rec2, hA, b3, B2, 0, N_NODES);
    spmm_half<<<spmm_grid, 256, 0, stream>>>(row_ptr, rec2, hB, b3, B2, 1, N_NODES);

    // ---- pool + head ----
    hipMemsetAsync(G, 0, (size_t)N_GRAPHS * F_HID * sizeof(float), stream);
    pool_seg<<<pool_grid, 256, 0, stream>>>(B2, seg, G, N_NODES);
    head_mlp<<<N_GRAPHS, 64, 0, stream>>>(G, Wd1, bd1, Wd2, bd2, Wd3, bd3, out);
}

// Round 8
// 398.769 us; speedup vs baseline: 1.1128x; 1.1128x over previous
//
#include <hip/hip_runtime.h>
#include <math.h>

#define N_NODES 100000
#define N_EDGES 3200000
#define N_GRAPHS 512
#define D_FEAT 128
#define F_HID 32

#define RPB 128                 // rows per bucket (row >> 7)
#define NB 782                  // ceil(100000/128)
#define CAP 5120                // fixed bucket capacity (mean 4092 -> 16 sigma margin)
#define CHUNK 4096              // edges per multisplit block
#define SBS 512                 // scatter block size
#define NCHUNK ((N_EDGES + CHUNK - 1) / CHUNK)   // 782

// ---- bf16 helpers (RNE, finite values only) ----
static __device__ __forceinline__ unsigned f2bf(float f) {
    unsigned u = __float_as_uint(f);
    return (u + 0x7FFFu + ((u >> 16) & 1u)) >> 16;
}
static __device__ __forceinline__ unsigned pack_bf2(float a, float b) {
    return (f2bf(b) << 16) | f2bf(a);
}
static __device__ __forceinline__ float bf_lo(unsigned u) { return __uint_as_float(u << 16); }
static __device__ __forceinline__ float bf_hi(unsigned u) { return __uint_as_float(u & 0xFFFF0000u); }

// ---------------- GEMM1: x[N,128] @ W[128,32] -> bf16 [N,32] ----------------
__global__ void gemm128x32(const float* __restrict__ x, const float* __restrict__ W,
                           unsigned short* __restrict__ outb, int n_nodes) {
    __shared__ float Ws[128 * 32];
    for (int i = threadIdx.x; i < 128 * 32; i += 256) Ws[i] = W[i];
    __syncthreads();
    const int fg = threadIdx.x & 7;
    const int nl = threadIdx.x >> 3;
    const int node = blockIdx.x * 32 + nl;
    if (node >= n_nodes) return;
    const float4* x4 = (const float4*)(x + (size_t)node * 128);
    const float4* Ws4 = (const float4*)Ws;
    float4 acc = make_float4(0.f, 0.f, 0.f, 0.f);
    for (int kk = 0; kk < 32; ++kk) {
        float4 xv = x4[kk];
        int k = kk * 4;
        float4 w0 = Ws4[(k + 0) * 8 + fg];
        float4 w1 = Ws4[(k + 1) * 8 + fg];
        float4 w2 = Ws4[(k + 2) * 8 + fg];
        float4 w3 = Ws4[(k + 3) * 8 + fg];
        acc.x += xv.x * w0.x + xv.y * w1.x + xv.z * w2.x + xv.w * w3.x;
        acc.y += xv.x * w0.y + xv.y * w1.y + xv.z * w2.y + xv.w * w3.y;
        acc.z += xv.x * w0.z + xv.y * w1.z + xv.z * w2.z + xv.w * w3.z;
        acc.w += xv.x * w0.w + xv.y * w1.w + xv.z * w2.w + xv.w * w3.w;
    }
    uint2 o = make_uint2(pack_bf2(acc.x, acc.y), pack_bf2(acc.z, acc.w));
    ((uint2*)(outb + (size_t)node * 32))[fg] = o;
}

// ---------------- GEMM: h[N,32] (fp32) @ W[32,32] -> bf16 [N,32] ----------------
__global__ void gemm32x32(const float* __restrict__ h, const float* __restrict__ W,
                          unsigned short* __restrict__ outb, int n_nodes) {
    __shared__ float Ws[32 * 32];
    for (int i = threadIdx.x; i < 32 * 32; i += 256) Ws[i] = W[i];
    __syncthreads();
    const int fg = threadIdx.x & 7;
    const int nl = threadIdx.x >> 3;
    const int node = blockIdx.x * 32 + nl;
    if (node >= n_nodes) return;
    const float4* h4 = (const float4*)(h + (size_t)node * 32);
    const float4* Ws4 = (const float4*)Ws;
    float4 acc = make_float4(0.f, 0.f, 0.f, 0.f);
    for (int kk = 0; kk < 8; ++kk) {
        float4 hv = h4[kk];
        int k = kk * 4;
        float4 w0 = Ws4[(k + 0) * 8 + fg];
        float4 w1 = Ws4[(k + 1) * 8 + fg];
        float4 w2 = Ws4[(k + 2) * 8 + fg];
        float4 w3 = Ws4[(k + 3) * 8 + fg];
        acc.x += hv.x * w0.x + hv.y * w1.x + hv.z * w2.x + hv.w * w3.x;
        acc.y += hv.x * w0.y + hv.y * w1.y + hv.z * w2.y + hv.w * w3.y;
        acc.z += hv.x * w0.z + hv.y * w1.z + hv.z * w2.z + hv.w * w3.z;
        acc.w += hv.x * w0.w + hv.y * w1.w + hv.z * w2.w + hv.w * w3.w;
    }
    uint2 o = make_uint2(pack_bf2(acc.x, acc.y), pack_bf2(acc.z, acc.w));
    ((uint2*)(outb + (size_t)node * 32))[fg] = o;
}

// ================= stage 0: cursor init (fixed-capacity buckets) =================
__global__ void init_cursor(int* __restrict__ cursor) {
    int t = blockIdx.x * blockDim.x + threadIdx.x;
    if (t < NB) cursor[t] = t * CAP;
}

// ====== stage 1: bucket multisplit, 512 threads / 4096 edges, LDS-staged ======
__global__ __launch_bounds__(SBS) void bucket_scatter(
        const int* __restrict__ row, const int* __restrict__ col,
        const float* __restrict__ w, int* __restrict__ cursor,
        uint2* __restrict__ rec, int n_edges) {
    __shared__ uint2 srt[CHUNK];      // 32 KB
    __shared__ int hist[NB];
    __shared__ int lofs[NB + 1];
    __shared__ int lbase[NB];
    __shared__ int tsum[SBS];
    const int t = threadIdx.x;
    const int base = blockIdx.x * CHUNK;
    const int count = min(CHUNK, n_edges - base);

    for (int i = t; i < NB; i += SBS) hist[i] = 0;
    __syncthreads();
    int rloc[CHUNK / SBS];            // cache row[] between passes
    #pragma unroll
    for (int j = 0; j < CHUNK / SBS; ++j) {
        int i = t + j * SBS;
        int r = -1;
        if (i < count) { r = row[base + i]; atomicAdd(&hist[r >> 7], 1); }
        rloc[j] = r;
    }
    __syncthreads();
    // two-per-thread exclusive scan of hist[NB]
    int v0 = 0, v1 = 0;
    {
        int i0 = t * 2, i1 = t * 2 + 1;
        if (i0 < NB) v0 = hist[i0];
        if (i1 < NB) v1 = hist[i1];
    }
    int s0 = v0 + v1;
    tsum[t] = s0;
    __syncthreads();
    for (int off = 1; off < SBS; off <<= 1) {
        int add = (t >= off) ? tsum[t - off] : 0;
        __syncthreads();
        tsum[t] += add;
        __syncthreads();
    }
    {
        int excl = tsum[t] - s0;
        int i0 = t * 2, i1 = t * 2 + 1;
        if (i0 < NB) lofs[i0] = excl;
        if (i1 < NB) lofs[i1] = excl + v0;
    }
    if (t == SBS - 1) lofs[NB] = tsum[SBS - 1];
    __syncthreads();
    for (int i = t; i < NB; i += SBS) {
        int c = hist[i];
        lbase[i] = c ? atomicAdd(&cursor[i], c) : 0;
        hist[i] = 0;
    }
    __syncthreads();
    #pragma unroll
    for (int j = 0; j < CHUNK / SBS; ++j) {
        int i = t + j * SBS;
        if (i < count) {
            int e = base + i;
            int r = rloc[j];
            int b = r >> 7;
            int pos = lofs[b] + atomicAdd(&hist[b], 1);
            srt[pos] = make_uint2(((unsigned)(r & 127) << 17) | (unsigned)col[e],
                                  __float_as_uint(w[e]));
        }
    }
    __syncthreads();
    // coalesced write-out
    for (int i = t; i < count; i += SBS) {
        uint2 vv = srt[i];
        int lo = 0, hi = NB;
        while (hi - lo > 1) {
            int mid = (lo + hi) >> 1;
            if (lofs[mid] <= i) lo = mid; else hi = mid;
        }
        rec[lbase[lo] + (i - lofs[lo])] = vv;
    }
}

// ================= stage 2: compact-base scan over bucket counts =================
__global__ void scan_nb(const int* __restrict__ cursor, int* __restrict__ bbase) {
    __shared__ int s[1024];
    const int t = threadIdx.x;
    int v = (t < NB) ? (cursor[t] - t * CAP) : 0;
    s[t] = v;
    __syncthreads();
    for (int off = 1; off < 1024; off <<= 1) {
        int add = (t >= off) ? s[t - off] : 0;
        __syncthreads();
        s[t] += add;
        __syncthreads();
    }
    if (t < NB) bbase[t] = s[t] - v;
    if (t == NB - 1) bbase[NB] = s[t];
}

// ====== stage 3: per-bucket counting sort -> compact CSR, 4 B records ======
// rec2[i] = (w_bf16_no_sign:15) << 17 | col:17
__global__ __launch_bounds__(512) void bucket_sort(
        const int* __restrict__ cursor, const int* __restrict__ bbase,
        const uint2* __restrict__ rec, unsigned* __restrict__ rec2,
        int* __restrict__ row_ptr, int n_nodes) {
    __shared__ unsigned srt[CAP];     // 20 KB
    __shared__ int hist[RPB];
    __shared__ int lofs[RPB];
    const int t = threadIdx.x;
    const int b = blockIdx.x;
    const int sbase = b * CAP;
    const int cnt = cursor[b] - sbase;
    const int gbase = bbase[b];

    if (t < RPB) hist[t] = 0;
    __syncthreads();
    for (int i = t; i < cnt; i += 512)
        atomicAdd(&hist[rec[sbase + i].x >> 17], 1);
    __syncthreads();
    if (t < RPB) lofs[t] = hist[t];
    __syncthreads();
    for (int off = 1; off < RPB; off <<= 1) {
        int v = (t < RPB && t >= off) ? lofs[t - off] : 0;
        __syncthreads();
        if (t < RPB) lofs[t] += v;
        __syncthreads();
    }
    if (t < RPB) {
        int excl = lofs[t] - hist[t];
        int gr = b * RPB + t;
        if (gr <= n_nodes) row_ptr[gr] = gbase + excl;
        hist[t] = excl;               // reuse as placement cursor
    }
    __syncthreads();
    for (int i = t; i < cnt; i += 512) {
        uint2 v = rec[sbase + i];
        int pos = atomicAdd(&hist[v.x >> 17], 1);
        unsigned wb = f2bf(__uint_as_float(v.y)) & 0x7FFFu;   // w > 0: drop sign
        srt[pos] = (wb << 17) | (v.x & 0x1FFFFu);
    }
    __syncthreads();
    for (int i = t; i < cnt; i += 512)
        rec2[gbase + i] = srt[i];
}

// ====== SPMM (CSR gather from bf16 h[N,32], 4 B records) + bias + ELU ======
// 8 lanes per node (one uint2 = 4 bf16 feats each); 32 nodes / 256-block; x8 unroll.
__global__ void spmm_csr(const int* __restrict__ rp, const unsigned* __restrict__ rec2,
                         const unsigned short* __restrict__ hb, const float* __restrict__ b,
                         float* __restrict__ out, int n_nodes) {
    const int fg = threadIdx.x & 7;
    const int node = blockIdx.x * 32 + (threadIdx.x >> 3);
    if (node >= n_nodes) return;
    const int s = rp[node], e = rp[node + 1];
    const uint2* h2 = (const uint2*)hb;   // 4 bf16 per uint2, row stride 8
    float4 acc = make_float4(0.f, 0.f, 0.f, 0.f);
    int i = s;
    for (; i + 8 <= e; i += 8) {
        unsigned p[8];
        uint2 g[8];
        #pragma unroll
        for (int j = 0; j < 8; ++j) p[j] = rec2[i + j];
        #pragma unroll
        for (int j = 0; j < 8; ++j) g[j] = h2[(size_t)(p[j] & 0x1FFFF) * 8 + fg];
        #pragma unroll
        for (int j = 0; j < 8; ++j) {
            float wj = __uint_as_float((p[j] >> 17) << 16);
            acc.x += wj * bf_lo(g[j].x);
            acc.y += wj * bf_hi(g[j].x);
            acc.z += wj * bf_lo(g[j].y);
            acc.w += wj * bf_hi(g[j].y);
        }
    }
    for (; i < e; ++i) {
        unsigned p0 = rec2[i];
        uint2 g0 = h2[(size_t)(p0 & 0x1FFFF) * 8 + fg];
        float w0 = __uint_as_float((p0 >> 17) << 16);
        acc.x += w0 * bf_lo(g0.x); acc.y += w0 * bf_hi(g0.x);
        acc.z += w0 * bf_lo(g0.y); acc.w += w0 * bf_hi(g0.y);
    }
    float4 bv = ((const float4*)b)[fg];
    acc.x += bv.x; acc.y += bv.y; acc.z += bv.z; acc.w += bv.w;
    acc.x = acc.x > 0.f ? acc.x : (expf(acc.x) - 1.f);
    acc.y = acc.y > 0.f ? acc.y : (expf(acc.y) - 1.f);
    acc.z = acc.z > 0.f ? acc.z : (expf(acc.z) - 1.f);
    acc.w = acc.w > 0.f ? acc.w : (expf(acc.w) - 1.f);
    ((float4*)(out + (size_t)node * 32))[fg] = acc;
}

// ================= pool: sorted seg run-accumulation =================
__global__ void pool_seg(const float* __restrict__ h, const int* __restrict__ seg,
                         float* __restrict__ g, int n_nodes) {
    const int t = threadIdx.x;
    const int f = t & 31;
    const int sub = t >> 5;
    const int base = blockIdx.x * 512;
    float run = 0.f;
    int cur = -1;
    for (int i = 0; i < 64; ++i) {
        int node = base + sub + i * 8;
        if (node >= n_nodes) break;
        int sg = seg[node];
        if (sg != cur) {
            if (cur >= 0) atomicAdd(&g[(size_t)cur * 32 + f], run);
            cur = sg;
            run = 0.f;
        }
        run += h[(size_t)node * 32 + f];
    }
    if (cur >= 0) atomicAdd(&g[(size_t)cur * 32 + f], run);
}

// ================= MLP head =================
__global__ void head_mlp(const float* __restrict__ g,
                         const float* __restrict__ Wd1, const float* __restrict__ bd1,
                         const float* __restrict__ Wd2, const float* __restrict__ bd2,
                         const float* __restrict__ Wd3, const float* __restrict__ bd3,
                         float* __restrict__ out) {
    __shared__ float gr[32];
    __shared__ float s1[64];
    __shared__ float s2[32];
    const int gid = blockIdx.x;
    const int t = threadIdx.x;
    if (t < 32) gr[t] = g[(size_t)gid * 32 + t];
    __syncthreads();
    float a = bd1[t];
    for (int k = 0; k < 32; ++k) a += gr[k] * Wd1[k * 64 + t];
    s1[t] = fmaxf(a, 0.f);
    __syncthreads();
    if (t < 32) {
        float a2 = bd2[t];
        for (int k = 0; k < 64; ++k) a2 += s1[k] * Wd2[k * 32 + t];
        s2[t] = fmaxf(a2, 0.f);
    }
    __syncthreads();
    if (t == 0) {
        float a3 = bd3[0];
        for (int k = 0; k < 32; ++k) a3 += s2[k] * Wd3[k];
        out[gid] = 1.f / (1.f + expf(-a3));
    }
}

extern "C" void kernel_launch(void* const* d_in, const int* in_sizes, int n_in,
                              void* d_out, int out_size, void* d_ws, size_t ws_size,
                              hipStream_t stream) {
    const float* x   = (const float*)d_in[0];
    const int*   ei  = (const int*)d_in[1];
    const float* ew  = (const float*)d_in[2];
    const int*   seg = (const int*)d_in[3];
    const float* W1  = (const float*)d_in[4];
    const float* b1  = (const float*)d_in[5];
    const float* W2  = (const float*)d_in[6];
    const float* b2  = (const float*)d_in[7];
    const float* W3  = (const float*)d_in[8];
    const float* b3  = (const float*)d_in[9];
    const float* Wd1 = (const float*)d_in[10];
    const float* bd1 = (const float*)d_in[11];
    const float* Wd2 = (const float*)d_in[12];
    const float* bd2 = (const float*)d_in[13];
    const float* Wd3 = (const float*)d_in[14];
    const float* bd3 = (const float*)d_in[15];
    float* out = (float*)d_out;

    const int* rowp = ei;
    const int* colp = ei + N_EDGES;

    const size_t NF  = (size_t)N_NODES * F_HID;
    const size_t REC_BYTES = (size_t)NB * CAP * sizeof(uint2);  // 32.03 MB

    // region A: rec (32 MB) during build; hb (6.4 MB bf16) + B2 (12.8 MB fp32) overlay
    char*  wsb     = (char*)d_ws;
    uint2* rec     = (uint2*)wsb;
    unsigned short* hb = (unsigned short*)wsb;              // bf16 [N,32]
    float* B2      = (float*)(wsb + NF * sizeof(unsigned short));  // fp32 [N,32]
    unsigned* rec2 = (unsigned*)(wsb + REC_BYTES);          // [E] 4 B records
    int*   cursor  = (int*)(rec2 + N_EDGES);                // [NB]
    int*   bbase   = cursor + NB;                           // [NB+1]
    int*   row_ptr = bbase + NB + 1;                        // [N+1]
    float* G       = (float*)(row_ptr + N_NODES + 1);       // [512,32]

    const int gemm_grid = (N_NODES + 31) / 32;
    const int pool_grid = (N_NODES + 511) / 512;

    // ---- CSR build (once per call) ----
    init_cursor<<<(NB + 255) / 256, 256, 0, stream>>>(cursor);
    bucket_scatter<<<NCHUNK, SBS, 0, stream>>>(rowp, colp, ew, cursor, rec, N_EDGES);
    scan_nb<<<1, 1024, 0, stream>>>(cursor, bbase);
    bucket_sort<<<NB, 512, 0, stream>>>(cursor, bbase, rec, rec2, row_ptr, N_NODES);

    // ---- layer 1 ----
    gemm128x32<<<gemm_grid, 256, 0, stream>>>(x, W1, hb, N_NODES);
    spmm_csr<<<gemm_grid, 256, 0, stream>>>(row_ptr, rec2, hb, b1, B2, N_NODES);

    // ---- layer 2 ----
    gemm32x32<<<gemm_grid, 256, 0, stream>>>(B2, W2, hb, N_NODES);
    spmm_csr<<<gemm_grid, 256, 0, stream>>>(row_ptr, rec2, hb, b2, B2, N_NODES);

    // ---- layer 3 ----
    gemm32x32<<<gemm_grid, 256, 0, stream>>>(B2, W3, hb, N_NODES);
    spmm_csr<<<gemm_grid, 256, 0, stream>>>(row_ptr, rec2, hb, b3, B2, N_NODES);

    // ---- pool + head ----
    hipMemsetAsync(G, 0, (size_t)N_GRAPHS * F_HID * sizeof(float), stream);
    pool_seg<<<pool_grid, 256, 0, stream>>>(B2, seg, G, N_NODES);
    head_mlp<<<N_GRAPHS, 64, 0, stream>>>(G, Wd1, bd1, Wd2, bd2, Wd3, bd3, out);
}

// Round 9
// 360.552 us; speedup vs baseline: 1.2308x; 1.1060x over previous
//
#include <hip/hip_runtime.h>
#include <math.h>

#define N_NODES 100000
#define N_EDGES 3200000
#define N_GRAPHS 512
#define D_FEAT 128
#define F_HID 32

#define RPB 128                 // rows per bucket (row >> 7)
#define NB 782                  // ceil(100000/128)
#define CAP 5120                // fixed bucket capacity (mean 4092 -> 16 sigma margin)
#define CHUNK 8192              // edges per multisplit block
#define SBS 1024                // scatter block size
#define NCHUNK ((N_EDGES + CHUNK - 1) / CHUNK)   // 391

// ---- bf16 helpers (RNE, finite values only) ----
static __device__ __forceinline__ unsigned f2bf(float f) {
    unsigned u = __float_as_uint(f);
    return (u + 0x7FFFu + ((u >> 16) & 1u)) >> 16;
}
static __device__ __forceinline__ unsigned pack_bf2(float a, float b) {
    return (f2bf(b) << 16) | f2bf(a);
}
static __device__ __forceinline__ float bf_lo(unsigned u) { return __uint_as_float(u << 16); }
static __device__ __forceinline__ float bf_hi(unsigned u) { return __uint_as_float(u & 0xFFFF0000u); }

// ---------------- GEMM1: x[N,128] @ W[128,32] -> bf16 [N,32] ----------------
__global__ void gemm128x32(const float* __restrict__ x, const float* __restrict__ W,
                           unsigned short* __restrict__ outb, int n_nodes) {
    __shared__ float Ws[128 * 32];
    for (int i = threadIdx.x; i < 128 * 32; i += 256) Ws[i] = W[i];
    __syncthreads();
    const int fg = threadIdx.x & 7;
    const int nl = threadIdx.x >> 3;
    const int node = blockIdx.x * 32 + nl;
    if (node >= n_nodes) return;
    const float4* x4 = (const float4*)(x + (size_t)node * 128);
    const float4* Ws4 = (const float4*)Ws;
    float4 acc = make_float4(0.f, 0.f, 0.f, 0.f);
    for (int kk = 0; kk < 32; ++kk) {
        float4 xv = x4[kk];
        int k = kk * 4;
        float4 w0 = Ws4[(k + 0) * 8 + fg];
        float4 w1 = Ws4[(k + 1) * 8 + fg];
        float4 w2 = Ws4[(k + 2) * 8 + fg];
        float4 w3 = Ws4[(k + 3) * 8 + fg];
        acc.x += xv.x * w0.x + xv.y * w1.x + xv.z * w2.x + xv.w * w3.x;
        acc.y += xv.x * w0.y + xv.y * w1.y + xv.z * w2.y + xv.w * w3.y;
        acc.z += xv.x * w0.z + xv.y * w1.z + xv.z * w2.z + xv.w * w3.z;
        acc.w += xv.x * w0.w + xv.y * w1.w + xv.z * w2.w + xv.w * w3.w;
    }
    uint2 o = make_uint2(pack_bf2(acc.x, acc.y), pack_bf2(acc.z, acc.w));
    ((uint2*)(outb + (size_t)node * 32))[fg] = o;
}

// ================= stage 0: cursor init (fixed-capacity buckets) =================
__global__ void init_cursor(int* __restrict__ cursor) {
    int t = blockIdx.x * blockDim.x + threadIdx.x;
    if (t < NB) cursor[t] = t * CAP;
}

// ====== stage 1: bucket multisplit, LDS-staged, hinted bucket lookup ======
__global__ __launch_bounds__(SBS) void bucket_scatter(
        const int* __restrict__ row, const int* __restrict__ col,
        const float* __restrict__ w, int* __restrict__ cursor,
        uint2* __restrict__ rec, int n_edges) {
    __shared__ uint2 srt[CHUNK];            // 64 KB
    __shared__ int hist[NB];
    __shared__ int lofs[NB + 1];
    __shared__ int lbase[NB];
    __shared__ int tsum[SBS];
    __shared__ unsigned short flr[CHUNK / 16];  // 1 KB bucket hints
    const int t = threadIdx.x;
    const int base = blockIdx.x * CHUNK;
    const int count = min(CHUNK, n_edges - base);

    if (t < NB) hist[t] = 0;
    __syncthreads();
    int rloc[CHUNK / SBS];                  // cache row[] between passes
    #pragma unroll
    for (int j = 0; j < CHUNK / SBS; ++j) {
        int i = t + j * SBS;
        int r = -1;
        if (i < count) { r = row[base + i]; atomicAdd(&hist[r >> 7], 1); }
        rloc[j] = r;
    }
    __syncthreads();
    int v = (t < NB) ? hist[t] : 0;
    tsum[t] = v;
    __syncthreads();
    for (int off = 1; off < SBS; off <<= 1) {
        int add = (t >= off) ? tsum[t - off] : 0;
        __syncthreads();
        tsum[t] += add;
        __syncthreads();
    }
    if (t < NB) lofs[t] = tsum[t] - v;
    if (t == SBS - 1) lofs[NB] = tsum[SBS - 1];
    __syncthreads();
    // reserve global ranges + reset hist; compute flr hints (one search per 16 slots)
    if (t < NB) {
        lbase[t] = v ? atomicAdd(&cursor[t], v) : 0;
        hist[t] = 0;
    }
    for (int q = t; q < CHUNK / 16; q += SBS) {
        int pos = q * 16;
        int lo = 0, hi = NB;
        while (hi - lo > 1) {
            int mid = (lo + hi) >> 1;
            if (lofs[mid] <= pos) lo = mid; else hi = mid;
        }
        flr[q] = (unsigned short)lo;
    }
    __syncthreads();
    #pragma unroll
    for (int j = 0; j < CHUNK / SBS; ++j) {
        int i = t + j * SBS;
        if (i < count) {
            int e = base + i;
            int r = rloc[j];
            int b = r >> 7;
            int pos = lofs[b] + atomicAdd(&hist[b], 1);
            srt[pos] = make_uint2(((unsigned)(r & 127) << 17) | (unsigned)col[e],
                                  __float_as_uint(w[e]));
        }
    }
    __syncthreads();
    // coalesced write-out; hinted linear bucket lookup
    for (int i = t; i < count; i += SBS) {
        uint2 vv = srt[i];
        int b = flr[i >> 4];
        while (lofs[b + 1] <= i) ++b;
        rec[lbase[b] + (i - lofs[b])] = vv;
    }
}

// ================= stage 2: compact-base scan over bucket counts =================
__global__ void scan_nb(const int* __restrict__ cursor, int* __restrict__ bbase) {
    __shared__ int s[1024];
    const int t = threadIdx.x;
    int v = (t < NB) ? (cursor[t] - t * CAP) : 0;
    s[t] = v;
    __syncthreads();
    for (int off = 1; off < 1024; off <<= 1) {
        int add = (t >= off) ? s[t - off] : 0;
        __syncthreads();
        s[t] += add;
        __syncthreads();
    }
    if (t < NB) bbase[t] = s[t] - v;
    if (t == NB - 1) bbase[NB] = s[t];
}

// ====== stage 3: per-bucket counting sort -> compact CSR, 4 B records ======
// rec2[i] = (w_bf16_no_sign:15) << 17 | col:17
__global__ __launch_bounds__(512) void bucket_sort(
        const int* __restrict__ cursor, const int* __restrict__ bbase,
        const uint2* __restrict__ rec, unsigned* __restrict__ rec2,
        int* __restrict__ row_ptr, int n_nodes) {
    __shared__ unsigned srt[CAP];     // 20 KB
    __shared__ int hist[RPB];
    __shared__ int lofs[RPB];
    const int t = threadIdx.x;
    const int b = blockIdx.x;
    const int sbase = b * CAP;
    const int cnt = cursor[b] - sbase;
    const int gbase = bbase[b];

    if (t < RPB) hist[t] = 0;
    __syncthreads();
    for (int i = t; i < cnt; i += 512)
        atomicAdd(&hist[rec[sbase + i].x >> 17], 1);
    __syncthreads();
    if (t < RPB) lofs[t] = hist[t];
    __syncthreads();
    for (int off = 1; off < RPB; off <<= 1) {
        int v = (t < RPB && t >= off) ? lofs[t - off] : 0;
        __syncthreads();
        if (t < RPB) lofs[t] += v;
        __syncthreads();
    }
    if (t < RPB) {
        int excl = lofs[t] - hist[t];
        int gr = b * RPB + t;
        if (gr <= n_nodes) row_ptr[gr] = gbase + excl;
        hist[t] = excl;               // reuse as placement cursor
    }
    __syncthreads();
    for (int i = t; i < cnt; i += 512) {
        uint2 v = rec[sbase + i];
        int pos = atomicAdd(&hist[v.x >> 17], 1);
        unsigned wb = f2bf(__uint_as_float(v.y)) & 0x7FFFu;   // w > 0: drop sign
        srt[pos] = (wb << 17) | (v.x & 0x1FFFFu);
    }
    __syncthreads();
    for (int i = t; i < cnt; i += 512)
        rec2[gbase + i] = srt[i];
}

// ====== fused SPMM: act = ELU(A.h + b); then either project @Wn -> bf16,
//        or write act as fp32 (last layer). 8 lanes/node, 32 nodes/block. ======
__global__ __launch_bounds__(256) void spmm_fused(
        const int* __restrict__ rp, const unsigned* __restrict__ rec2,
        const unsigned short* __restrict__ hb_in, const float* __restrict__ bias,
        const float* __restrict__ Wn,          // 32x32 or nullptr
        unsigned short* __restrict__ hb_out,   // used if Wn != nullptr
        float* __restrict__ f32_out,           // used if Wn == nullptr
        int n_nodes) {
    __shared__ float Ws[32 * 32];     // next-layer W
    __shared__ float vt[32 * 33];     // activation staging (padded)
    const int t = threadIdx.x;
    if (Wn) for (int i = t; i < 1024; i += 256) Ws[i] = Wn[i];
    const int fg = t & 7;
    const int nl = t >> 3;
    const int node = blockIdx.x * 32 + nl;    // grid covers N exactly (3125*32)
    const bool valid = node < n_nodes;
    const int s = valid ? rp[node] : 0;
    const int e = valid ? rp[node + 1] : 0;
    const uint2* h2 = (const uint2*)hb_in;    // 4 bf16 per uint2, row stride 8
    float4 acc = make_float4(0.f, 0.f, 0.f, 0.f);
    int i = s;
    // head: align i to 4 for uint4 record loads
    for (; i < e && (i & 3); ++i) {
        unsigned p0 = rec2[i];
        uint2 g0 = h2[(size_t)(p0 & 0x1FFFF) * 8 + fg];
        float w0 = __uint_as_float((p0 >> 17) << 16);
        acc.x += w0 * bf_lo(g0.x); acc.y += w0 * bf_hi(g0.x);
        acc.z += w0 * bf_lo(g0.y); acc.w += w0 * bf_hi(g0.y);
    }
    for (; i + 8 <= e; i += 8) {
        uint4 pa = *(const uint4*)(rec2 + i);
        uint4 pb = *(const uint4*)(rec2 + i + 4);
        unsigned p[8] = {pa.x, pa.y, pa.z, pa.w, pb.x, pb.y, pb.z, pb.w};
        uint2 g[8];
        #pragma unroll
        for (int j = 0; j < 8; ++j) g[j] = h2[(size_t)(p[j] & 0x1FFFF) * 8 + fg];
        #pragma unroll
        for (int j = 0; j < 8; ++j) {
            float wj = __uint_as_float((p[j] >> 17) << 16);
            acc.x += wj * bf_lo(g[j].x);
            acc.y += wj * bf_hi(g[j].x);
            acc.z += wj * bf_lo(g[j].y);
            acc.w += wj * bf_hi(g[j].y);
        }
    }
    for (; i < e; ++i) {
        unsigned p0 = rec2[i];
        uint2 g0 = h2[(size_t)(p0 & 0x1FFFF) * 8 + fg];
        float w0 = __uint_as_float((p0 >> 17) << 16);
        acc.x += w0 * bf_lo(g0.x); acc.y += w0 * bf_hi(g0.x);
        acc.z += w0 * bf_lo(g0.y); acc.w += w0 * bf_hi(g0.y);
    }
    float4 bv = ((const float4*)bias)[fg];
    acc.x += bv.x; acc.y += bv.y; acc.z += bv.z; acc.w += bv.w;
    acc.x = acc.x > 0.f ? acc.x : (expf(acc.x) - 1.f);
    acc.y = acc.y > 0.f ? acc.y : (expf(acc.y) - 1.f);
    acc.z = acc.z > 0.f ? acc.z : (expf(acc.z) - 1.f);
    acc.w = acc.w > 0.f ? acc.w : (expf(acc.w) - 1.f);

    if (!Wn) {
        if (valid) ((float4*)(f32_out + (size_t)node * 32))[fg] = acc;
        return;
    }
    // stage act in LDS, project @ Wn, emit bf16
    {
        float* vr = vt + nl * 33 + fg * 4;
        vr[0] = acc.x; vr[1] = acc.y; vr[2] = acc.z; vr[3] = acc.w;
    }
    __syncthreads();
    const float4* Ws4 = (const float4*)Ws;
    const float* vrow = vt + nl * 33;
    float4 o = make_float4(0.f, 0.f, 0.f, 0.f);
    #pragma unroll 8
    for (int k = 0; k < 32; ++k) {
        float vk = vrow[k];
        float4 wv = Ws4[k * 8 + fg];
        o.x += vk * wv.x; o.y += vk * wv.y; o.z += vk * wv.z; o.w += vk * wv.w;
    }
    if (valid) {
        uint2 ob = make_uint2(pack_bf2(o.x, o.y), pack_bf2(o.z, o.w));
        ((uint2*)(hb_out + (size_t)node * 32))[fg] = ob;
    }
}

// ================= pool: sorted seg run-accumulation =================
__global__ void pool_seg(const float* __restrict__ h, const int* __restrict__ seg,
                         float* __restrict__ g, int n_nodes) {
    const int t = threadIdx.x;
    const int f = t & 31;
    const int sub = t >> 5;
    const int base = blockIdx.x * 512;
    float run = 0.f;
    int cur = -1;
    for (int i = 0; i < 64; ++i) {
        int node = base + sub + i * 8;
        if (node >= n_nodes) break;
        int sg = seg[node];
        if (sg != cur) {
            if (cur >= 0) atomicAdd(&g[(size_t)cur * 32 + f], run);
            cur = sg;
            run = 0.f;
        }
        run += h[(size_t)node * 32 + f];
    }
    if (cur >= 0) atomicAdd(&g[(size_t)cur * 32 + f], run);
}

// ================= MLP head =================
__global__ void head_mlp(const float* __restrict__ g,
                         const float* __restrict__ Wd1, const float* __restrict__ bd1,
                         const float* __restrict__ Wd2, const float* __restrict__ bd2,
                         const float* __restrict__ Wd3, const float* __restrict__ bd3,
                         float* __restrict__ out) {
    __shared__ float gr[32];
    __shared__ float s1[64];
    __shared__ float s2[32];
    const int gid = blockIdx.x;
    const int t = threadIdx.x;
    if (t < 32) gr[t] = g[(size_t)gid * 32 + t];
    __syncthreads();
    float a = bd1[t];
    for (int k = 0; k < 32; ++k) a += gr[k] * Wd1[k * 64 + t];
    s1[t] = fmaxf(a, 0.f);
    __syncthreads();
    if (t < 32) {
        float a2 = bd2[t];
        for (int k = 0; k < 64; ++k) a2 += s1[k] * Wd2[k * 32 + t];
        s2[t] = fmaxf(a2, 0.f);
    }
    __syncthreads();
    if (t == 0) {
        float a3 = bd3[0];
        for (int k = 0; k < 32; ++k) a3 += s2[k] * Wd3[k];
        out[gid] = 1.f / (1.f + expf(-a3));
    }
}

extern "C" void kernel_launch(void* const* d_in, const int* in_sizes, int n_in,
                              void* d_out, int out_size, void* d_ws, size_t ws_size,
                              hipStream_t stream) {
    const float* x   = (const float*)d_in[0];
    const int*   ei  = (const int*)d_in[1];
    const float* ew  = (const float*)d_in[2];
    const int*   seg = (const int*)d_in[3];
    const float* W1  = (const float*)d_in[4];
    const float* b1  = (const float*)d_in[5];
    const float* W2  = (const float*)d_in[6];
    const float* b2  = (const float*)d_in[7];
    const float* W3  = (const float*)d_in[8];
    const float* b3  = (const float*)d_in[9];
    const float* Wd1 = (const float*)d_in[10];
    const float* bd1 = (const float*)d_in[11];
    const float* Wd2 = (const float*)d_in[12];
    const float* bd2 = (const float*)d_in[13];
    const float* Wd3 = (const float*)d_in[14];
    const float* bd3 = (const float*)d_in[15];
    float* out = (float*)d_out;

    const int* rowp = ei;
    const int* colp = ei + N_EDGES;

    const size_t NF  = (size_t)N_NODES * F_HID;
    const size_t REC_BYTES = (size_t)NB * CAP * sizeof(uint2);  // 32.03 MB

    // region A: rec (32 MB) during build; hbA (6.4) + hbB (6.4) + B2 (12.8) overlay
    char*  wsb     = (char*)d_ws;
    uint2* rec     = (uint2*)wsb;
    unsigned short* hbA = (unsigned short*)wsb;                 // bf16 [N,32]
    unsigned short* hbB = (unsigned short*)(wsb + NF * 2);      // bf16 [N,32]
    float* B2      = (float*)(wsb + NF * 4);                    // fp32 [N,32]
    unsigned* rec2 = (unsigned*)(wsb + REC_BYTES);              // [E] 4 B records
    int*   cursor  = (int*)(rec2 + N_EDGES);                    // [NB]
    int*   bbase   = cursor + NB;                               // [NB+1]
    int*   row_ptr = bbase + NB + 1;                            // [N+1]
    float* G       = (float*)(row_ptr + N_NODES + 1);           // [512,32]

    const int gemm_grid = (N_NODES + 31) / 32;   // 3125 (exact)
    const int pool_grid = (N_NODES + 511) / 512;

    // ---- CSR build (once per call) ----
    init_cursor<<<(NB + 255) / 256, 256, 0, stream>>>(cursor);
    bucket_scatter<<<NCHUNK, SBS, 0, stream>>>(rowp, colp, ew, cursor, rec, N_EDGES);
    scan_nb<<<1, 1024, 0, stream>>>(cursor, bbase);
    bucket_sort<<<NB, 512, 0, stream>>>(cursor, bbase, rec, rec2, row_ptr, N_NODES);

    // ---- layer 1: project x@W1, then fused spmm(+b1,ELU) @W2 -> hbB ----
    gemm128x32<<<gemm_grid, 256, 0, stream>>>(x, W1, hbA, N_NODES);
    spmm_fused<<<gemm_grid, 256, 0, stream>>>(row_ptr, rec2, hbA, b1, W2, hbB, nullptr, N_NODES);

    // ---- layer 2: fused spmm(+b2,ELU) @W3 -> hbA ----
    spmm_fused<<<gemm_grid, 256, 0, stream>>>(row_ptr, rec2, hbB, b2, W3, hbA, nullptr, N_NODES);

    // ---- layer 3: fused spmm(+b3,ELU) -> fp32 B2 ----
    spmm_fused<<<gemm_grid, 256, 0, stream>>>(row_ptr, rec2, hbA, b3, nullptr, nullptr, B2, N_NODES);

    // ---- pool + head ----
    hipMemsetAsync(G, 0, (size_t)N_GRAPHS * F_HID * sizeof(float), stream);
    pool_seg<<<pool_grid, 256, 0, stream>>>(B2, seg, G, N_NODES);
    head_mlp<<<N_GRAPHS, 64, 0, stream>>>(G, Wd1, bd1, Wd2, bd2, Wd3, bd3, out);
}

// Round 10
// 354.227 us; speedup vs baseline: 1.2528x; 1.0179x over previous
//
#include <hip/hip_runtime.h>
#include <math.h>

#define N_NODES 100000
#define N_EDGES 3200000
#define N_GRAPHS 512
#define D_FEAT 128
#define F_HID 32

#define RPB 128                 // rows per bucket (row >> 7)
#define NB 782                  // ceil(100000/128)
#define CAP 5120                // fixed bucket capacity (mean 4092 -> 16 sigma margin)
#define CHUNK 8192              // edges per multisplit block
#define SBS 1024                // scatter block size
#define NCHUNK ((N_EDGES + CHUNK - 1) / CHUNK)   // 391
#define CTILES 16               // col tiles per row for gather locality (col >> 13)
#define NKEYS (RPB * CTILES)    // 2048 counting-sort keys

// ---- bf16 helpers (RNE, finite values only) ----
static __device__ __forceinline__ unsigned f2bf(float f) {
    unsigned u = __float_as_uint(f);
    return (u + 0x7FFFu + ((u >> 16) & 1u)) >> 16;
}
static __device__ __forceinline__ unsigned pack_bf2(float a, float b) {
    return (f2bf(b) << 16) | f2bf(a);
}
static __device__ __forceinline__ float bf_lo(unsigned u) { return __uint_as_float(u << 16); }
static __device__ __forceinline__ float bf_hi(unsigned u) { return __uint_as_float(u & 0xFFFF0000u); }

// ---------------- GEMM1: x[N,128] @ W[128,32] -> bf16 [N,32] ----------------
__global__ void gemm128x32(const float* __restrict__ x, const float* __restrict__ W,
                           unsigned short* __restrict__ outb, int n_nodes) {
    __shared__ float Ws[128 * 32];
    for (int i = threadIdx.x; i < 128 * 32; i += 256) Ws[i] = W[i];
    __syncthreads();
    const int fg = threadIdx.x & 7;
    const int nl = threadIdx.x >> 3;
    const int node = blockIdx.x * 32 + nl;
    if (node >= n_nodes) return;
    const float4* x4 = (const float4*)(x + (size_t)node * 128);
    const float4* Ws4 = (const float4*)Ws;
    float4 acc = make_float4(0.f, 0.f, 0.f, 0.f);
    for (int kk = 0; kk < 32; ++kk) {
        float4 xv = x4[kk];
        int k = kk * 4;
        float4 w0 = Ws4[(k + 0) * 8 + fg];
        float4 w1 = Ws4[(k + 1) * 8 + fg];
        float4 w2 = Ws4[(k + 2) * 8 + fg];
        float4 w3 = Ws4[(k + 3) * 8 + fg];
        acc.x += xv.x * w0.x + xv.y * w1.x + xv.z * w2.x + xv.w * w3.x;
        acc.y += xv.x * w0.y + xv.y * w1.y + xv.z * w2.y + xv.w * w3.y;
        acc.z += xv.x * w0.z + xv.y * w1.z + xv.z * w2.z + xv.w * w3.z;
        acc.w += xv.x * w0.w + xv.y * w1.w + xv.z * w2.w + xv.w * w3.w;
    }
    uint2 o = make_uint2(pack_bf2(acc.x, acc.y), pack_bf2(acc.z, acc.w));
    ((uint2*)(outb + (size_t)node * 32))[fg] = o;
}

// ================= stage 0: cursor init (fixed-capacity buckets) =================
__global__ void init_cursor(int* __restrict__ cursor) {
    int t = blockIdx.x * blockDim.x + threadIdx.x;
    if (t < NB) cursor[t] = t * CAP;
}

// ====== stage 1: bucket multisplit, LDS-staged, hinted bucket lookup ======
__global__ __launch_bounds__(SBS) void bucket_scatter(
        const int* __restrict__ row, const int* __restrict__ col,
        const float* __restrict__ w, int* __restrict__ cursor,
        uint2* __restrict__ rec, int n_edges) {
    __shared__ uint2 srt[CHUNK];            // 64 KB
    __shared__ int hist[NB];
    __shared__ int lofs[NB + 1];
    __shared__ int lbase[NB];
    __shared__ int tsum[SBS];
    __shared__ unsigned short flr[CHUNK / 16];  // 1 KB bucket hints
    const int t = threadIdx.x;
    const int base = blockIdx.x * CHUNK;
    const int count = min(CHUNK, n_edges - base);

    if (t < NB) hist[t] = 0;
    __syncthreads();
    int rloc[CHUNK / SBS];                  // cache row[] between passes
    #pragma unroll
    for (int j = 0; j < CHUNK / SBS; ++j) {
        int i = t + j * SBS;
        int r = -1;
        if (i < count) { r = row[base + i]; atomicAdd(&hist[r >> 7], 1); }
        rloc[j] = r;
    }
    __syncthreads();
    int v = (t < NB) ? hist[t] : 0;
    tsum[t] = v;
    __syncthreads();
    for (int off = 1; off < SBS; off <<= 1) {
        int add = (t >= off) ? tsum[t - off] : 0;
        __syncthreads();
        tsum[t] += add;
        __syncthreads();
    }
    if (t < NB) lofs[t] = tsum[t] - v;
    if (t == SBS - 1) lofs[NB] = tsum[SBS - 1];
    __syncthreads();
    // reserve global ranges + reset hist; compute flr hints (one search per 16 slots)
    if (t < NB) {
        lbase[t] = v ? atomicAdd(&cursor[t], v) : 0;
        hist[t] = 0;
    }
    for (int q = t; q < CHUNK / 16; q += SBS) {
        int pos = q * 16;
        int lo = 0, hi = NB;
        while (hi - lo > 1) {
            int mid = (lo + hi) >> 1;
            if (lofs[mid] <= pos) lo = mid; else hi = mid;
        }
        flr[q] = (unsigned short)lo;
    }
    __syncthreads();
    #pragma unroll
    for (int j = 0; j < CHUNK / SBS; ++j) {
        int i = t + j * SBS;
        if (i < count) {
            int e = base + i;
            int r = rloc[j];
            int b = r >> 7;
            int pos = lofs[b] + atomicAdd(&hist[b], 1);
            srt[pos] = make_uint2(((unsigned)(r & 127) << 17) | (unsigned)col[e],
                                  __float_as_uint(w[e]));
        }
    }
    __syncthreads();
    // coalesced write-out; hinted linear bucket lookup
    for (int i = t; i < count; i += SBS) {
        uint2 vv = srt[i];
        int b = flr[i >> 4];
        while (lofs[b + 1] <= i) ++b;
        rec[lbase[b] + (i - lofs[b])] = vv;
    }
}

// ================= stage 2: compact-base scan over bucket counts =================
__global__ void scan_nb(const int* __restrict__ cursor, int* __restrict__ bbase) {
    __shared__ int s[1024];
    const int t = threadIdx.x;
    int v = (t < NB) ? (cursor[t] - t * CAP) : 0;
    s[t] = v;
    __syncthreads();
    for (int off = 1; off < 1024; off <<= 1) {
        int add = (t >= off) ? s[t - off] : 0;
        __syncthreads();
        s[t] += add;
        __syncthreads();
    }
    if (t < NB) bbase[t] = s[t] - v;
    if (t == NB - 1) bbase[NB] = s[t];
}

// ====== stage 3: per-bucket counting sort by (row_local, col_tile) -> CSR ======
// rec2[i] = (w_bf16_no_sign:15) << 17 | col:17; each row's edges col-tile-ordered.
__global__ __launch_bounds__(512) void bucket_sort(
        const int* __restrict__ cursor, const int* __restrict__ bbase,
        const uint2* __restrict__ rec, unsigned* __restrict__ rec2,
        int* __restrict__ row_ptr, int n_nodes) {
    __shared__ unsigned srt[CAP];     // 20 KB
    __shared__ int hist[NKEYS];       // 8 KB
    __shared__ int lofs[NKEYS];       // 8 KB
    __shared__ int tsum[512];         // 2 KB
    const int t = threadIdx.x;
    const int b = blockIdx.x;
    const int sbase = b * CAP;
    const int cnt = cursor[b] - sbase;
    const int gbase = bbase[b];

    for (int i = t; i < NKEYS; i += 512) hist[i] = 0;
    __syncthreads();
    for (int i = t; i < cnt; i += 512) {
        unsigned rx = rec[sbase + i].x;
        int key = (rx >> 17) * CTILES + ((rx & 0x1FFFFu) >> 13);
        atomicAdd(&hist[key], 1);
    }
    __syncthreads();
    // exclusive scan over NKEYS: 4 keys per thread
    int vals[4];
    int s0 = 0;
    const int k4 = t * 4;
    #pragma unroll
    for (int j = 0; j < 4; ++j) { vals[j] = hist[k4 + j]; s0 += vals[j]; }
    tsum[t] = s0;
    __syncthreads();
    for (int off = 1; off < 512; off <<= 1) {
        int add = (t >= off) ? tsum[t - off] : 0;
        __syncthreads();
        tsum[t] += add;
        __syncthreads();
    }
    {
        int run = tsum[t] - s0;
        #pragma unroll
        for (int j = 0; j < 4; ++j) { lofs[k4 + j] = run; run += vals[j]; }
    }
    __syncthreads();
    // row_ptr at each row boundary (exclusive prefix at the row's first key)
    if (t < RPB) {
        int gr = b * RPB + t;
        if (gr <= n_nodes) row_ptr[gr] = gbase + lofs[t * CTILES];
    }
    // hist becomes the placement cursor
    for (int i = t; i < NKEYS; i += 512) hist[i] = lofs[i];
    __syncthreads();
    for (int i = t; i < cnt; i += 512) {
        uint2 v = rec[sbase + i];
        int key = (v.x >> 17) * CTILES + ((v.x & 0x1FFFFu) >> 13);
        int pos = atomicAdd(&hist[key], 1);
        unsigned wb = f2bf(__uint_as_float(v.y)) & 0x7FFFu;   // w > 0: drop sign
        srt[pos] = (wb << 17) | (v.x & 0x1FFFFu);
    }
    __syncthreads();
    for (int i = t; i < cnt; i += 512)
        rec2[gbase + i] = srt[i];
}

// ====== fused SPMM: act = ELU(A.h + b); then either project @Wn -> bf16,
//        or write act as fp32 (last layer). 8 lanes/node, 32 nodes/block. ======
__global__ __launch_bounds__(256) void spmm_fused(
        const int* __restrict__ rp, const unsigned* __restrict__ rec2,
        const unsigned short* __restrict__ hb_in, const float* __restrict__ bias,
        const float* __restrict__ Wn,          // 32x32 or nullptr
        unsigned short* __restrict__ hb_out,   // used if Wn != nullptr
        float* __restrict__ f32_out,           // used if Wn == nullptr
        int n_nodes) {
    __shared__ float Ws[32 * 32];     // next-layer W
    __shared__ float vt[32 * 33];     // activation staging (padded)
    const int t = threadIdx.x;
    if (Wn) for (int i = t; i < 1024; i += 256) Ws[i] = Wn[i];
    const int fg = t & 7;
    const int nl = t >> 3;
    const int node = blockIdx.x * 32 + nl;    // grid covers N exactly (3125*32)
    const bool valid = node < n_nodes;
    const int s = valid ? rp[node] : 0;
    const int e = valid ? rp[node + 1] : 0;
    const uint2* h2 = (const uint2*)hb_in;    // 4 bf16 per uint2, row stride 8
    float4 acc = make_float4(0.f, 0.f, 0.f, 0.f);
    int i = s;
    // head: align i to 4 for uint4 record loads
    for (; i < e && (i & 3); ++i) {
        unsigned p0 = rec2[i];
        uint2 g0 = h2[(size_t)(p0 & 0x1FFFF) * 8 + fg];
        float w0 = __uint_as_float((p0 >> 17) << 16);
        acc.x += w0 * bf_lo(g0.x); acc.y += w0 * bf_hi(g0.x);
        acc.z += w0 * bf_lo(g0.y); acc.w += w0 * bf_hi(g0.y);
    }
    for (; i + 8 <= e; i += 8) {
        uint4 pa = *(const uint4*)(rec2 + i);
        uint4 pb = *(const uint4*)(rec2 + i + 4);
        unsigned p[8] = {pa.x, pa.y, pa.z, pa.w, pb.x, pb.y, pb.z, pb.w};
        uint2 g[8];
        #pragma unroll
        for (int j = 0; j < 8; ++j) g[j] = h2[(size_t)(p[j] & 0x1FFFF) * 8 + fg];
        #pragma unroll
        for (int j = 0; j < 8; ++j) {
            float wj = __uint_as_float((p[j] >> 17) << 16);
            acc.x += wj * bf_lo(g[j].x);
            acc.y += wj * bf_hi(g[j].x);
            acc.z += wj * bf_lo(g[j].y);
            acc.w += wj * bf_hi(g[j].y);
        }
    }
    for (; i < e; ++i) {
        unsigned p0 = rec2[i];
        uint2 g0 = h2[(size_t)(p0 & 0x1FFFF) * 8 + fg];
        float w0 = __uint_as_float((p0 >> 17) << 16);
        acc.x += w0 * bf_lo(g0.x); acc.y += w0 * bf_hi(g0.x);
        acc.z += w0 * bf_lo(g0.y); acc.w += w0 * bf_hi(g0.y);
    }
    float4 bv = ((const float4*)bias)[fg];
    acc.x += bv.x; acc.y += bv.y; acc.z += bv.z; acc.w += bv.w;
    acc.x = acc.x > 0.f ? acc.x : (expf(acc.x) - 1.f);
    acc.y = acc.y > 0.f ? acc.y : (expf(acc.y) - 1.f);
    acc.z = acc.z > 0.f ? acc.z : (expf(acc.z) - 1.f);
    acc.w = acc.w > 0.f ? acc.w : (expf(acc.w) - 1.f);

    if (!Wn) {
        if (valid) ((float4*)(f32_out + (size_t)node * 32))[fg] = acc;
        return;
    }
    // stage act in LDS, project @ Wn, emit bf16
    {
        float* vr = vt + nl * 33 + fg * 4;
        vr[0] = acc.x; vr[1] = acc.y; vr[2] = acc.z; vr[3] = acc.w;
    }
    __syncthreads();
    const float4* Ws4 = (const float4*)Ws;
    const float* vrow = vt + nl * 33;
    float4 o = make_float4(0.f, 0.f, 0.f, 0.f);
    #pragma unroll 8
    for (int k = 0; k < 32; ++k) {
        float vk = vrow[k];
        float4 wv = Ws4[k * 8 + fg];
        o.x += vk * wv.x; o.y += vk * wv.y; o.z += vk * wv.z; o.w += vk * wv.w;
    }
    if (valid) {
        uint2 ob = make_uint2(pack_bf2(o.x, o.y), pack_bf2(o.z, o.w));
        ((uint2*)(hb_out + (size_t)node * 32))[fg] = ob;
    }
}

// ================= pool: sorted seg run-accumulation =================
__global__ void pool_seg(const float* __restrict__ h, const int* __restrict__ seg,
                         float* __restrict__ g, int n_nodes) {
    const int t = threadIdx.x;
    const int f = t & 31;
    const int sub = t >> 5;
    const int base = blockIdx.x * 512;
    float run = 0.f;
    int cur = -1;
    for (int i = 0; i < 64; ++i) {
        int node = base + sub + i * 8;
        if (node >= n_nodes) break;
        int sg = seg[node];
        if (sg != cur) {
            if (cur >= 0) atomicAdd(&g[(size_t)cur * 32 + f], run);
            cur = sg;
            run = 0.f;
        }
        run += h[(size_t)node * 32 + f];
    }
    if (cur >= 0) atomicAdd(&g[(size_t)cur * 32 + f], run);
}

// ================= MLP head =================
__global__ void head_mlp(const float* __restrict__ g,
                         const float* __restrict__ Wd1, const float* __restrict__ bd1,
                         const float* __restrict__ Wd2, const float* __restrict__ bd2,
                         const float* __restrict__ Wd3, const float* __restrict__ bd3,
                         float* __restrict__ out) {
    __shared__ float gr[32];
    __shared__ float s1[64];
    __shared__ float s2[32];
    const int gid = blockIdx.x;
    const int t = threadIdx.x;
    if (t < 32) gr[t] = g[(size_t)gid * 32 + t];
    __syncthreads();
    float a = bd1[t];
    for (int k = 0; k < 32; ++k) a += gr[k] * Wd1[k * 64 + t];
    s1[t] = fmaxf(a, 0.f);
    __syncthreads();
    if (t < 32) {
        float a2 = bd2[t];
        for (int k = 0; k < 64; ++k) a2 += s1[k] * Wd2[k * 32 + t];
        s2[t] = fmaxf(a2, 0.f);
    }
    __syncthreads();
    if (t == 0) {
        float a3 = bd3[0];
        for (int k = 0; k < 32; ++k) a3 += s2[k] * Wd3[k];
        out[gid] = 1.f / (1.f + expf(-a3));
    }
}

extern "C" void kernel_launch(void* const* d_in, const int* in_sizes, int n_in,
                              void* d_out, int out_size, void* d_ws, size_t ws_size,
                              hipStream_t stream) {
    const float* x   = (const float*)d_in[0];
    const int*   ei  = (const int*)d_in[1];
    const float* ew  = (const float*)d_in[2];
    const int*   seg = (const int*)d_in[3];
    const float* W1  = (const float*)d_in[4];
    const float* b1  = (const float*)d_in[5];
    const float* W2  = (const float*)d_in[6];
    const float* b2  = (const float*)d_in[7];
    const float* W3  = (const float*)d_in[8];
    const float* b3  = (const float*)d_in[9];
    const float* Wd1 = (const float*)d_in[10];
    const float* bd1 = (const float*)d_in[11];
    const float* Wd2 = (const float*)d_in[12];
    const float* bd2 = (const float*)d_in[13];
    const float* Wd3 = (const float*)d_in[14];
    const float* bd3 = (const float*)d_in[15];
    float* out = (float*)d_out;

    const int* rowp = ei;
    const int* colp = ei + N_EDGES;

    const size_t NF  = (size_t)N_NODES * F_HID;
    const size_t REC_BYTES = (size_t)NB * CAP * sizeof(uint2);  // 32.03 MB

    // region A: rec (32 MB) during build; hbA (6.4) + hbB (6.4) + B2 (12.8) overlay
    char*  wsb     = (char*)d_ws;
    uint2* rec     = (uint2*)wsb;
    unsigned short* hbA = (unsigned short*)wsb;                 // bf16 [N,32]
    unsigned short* hbB = (unsigned short*)(wsb + NF * 2);      // bf16 [N,32]
    float* B2      = (float*)(wsb + NF * 4);                    // fp32 [N,32]
    unsigned* rec2 = (unsigned*)(wsb + REC_BYTES);              // [E] 4 B records
    int*   cursor  = (int*)(rec2 + N_EDGES);                    // [NB]
    int*   bbase   = cursor + NB;                               // [NB+1]
    int*   row_ptr = bbase + NB + 1;                            // [N+1]
    float* G       = (float*)(row_ptr + N_NODES + 1);           // [512,32]

    const int gemm_grid = (N_NODES + 31) / 32;   // 3125 (exact)
    const int pool_grid = (N_NODES + 511) / 512;

    // ---- CSR build (once per call) ----
    init_cursor<<<(NB + 255) / 256, 256, 0, stream>>>(cursor);
    bucket_scatter<<<NCHUNK, SBS, 0, stream>>>(rowp, colp, ew, cursor, rec, N_EDGES);
    scan_nb<<<1, 1024, 0, stream>>>(cursor, bbase);
    bucket_sort<<<NB, 512, 0, stream>>>(cursor, bbase, rec, rec2, row_ptr, N_NODES);

    // ---- layer 1: project x@W1, then fused spmm(+b1,ELU) @W2 -> hbB ----
    gemm128x32<<<gemm_grid, 256, 0, stream>>>(x, W1, hbA, N_NODES);
    spmm_fused<<<gemm_grid, 256, 0, stream>>>(row_ptr, rec2, hbA, b1, W2, hbB, nullptr, N_NODES);

    // ---- layer 2: fused spmm(+b2,ELU) @W3 -> hbA ----
    spmm_fused<<<gemm_grid, 256, 0, stream>>>(row_ptr, rec2, hbB, b2, W3, hbA, nullptr, N_NODES);

    // ---- layer 3: fused spmm(+b3,ELU) -> fp32 B2 ----
    spmm_fused<<<gemm_grid, 256, 0, stream>>>(row_ptr, rec2, hbA, b3, nullptr, nullptr, B2, N_NODES);

    // ---- pool + head ----
    hipMemsetAsync(G, 0, (size_t)N_GRAPHS * F_HID * sizeof(float), stream);
    pool_seg<<<pool_grid, 256, 0, stream>>>(B2, seg, G, N_NODES);
    head_mlp<<<N_GRAPHS, 64, 0, stream>>>(G, Wd1, bd1, Wd2, bd2, Wd3, bd3, out);
}

// Round 11
// 318.870 us; speedup vs baseline: 1.3917x; 1.1109x over previous
//
#include <hip/hip_runtime.h>
#include <hip/hip_fp16.h>
#include <math.h>

#define N_NODES 100000
#define N_EDGES 3200000
#define N_GRAPHS 512
#define D_FEAT 128
#define F_HID 32

#define RPB 128                 // rows per bucket (row >> 7)
#define NB 782                  // ceil(100000/128)
#define CAP 5120                // fixed bucket capacity (mean 4092 -> 16 sigma margin)
#define CHUNK 8192              // edges per multisplit block
#define SBS 1024                // scatter block size
#define NCHUNK ((N_EDGES + CHUNK - 1) / CHUNK)   // 391
#define CTILES 16               // col tiles per row for gather locality (col >> 13)
#define NKEYS (RPB * CTILES)    // 2048 counting-sort keys
#define SPB 64                  // nodes per spmm block (256 threads / 4 lanes)

static __device__ __forceinline__ __half2 u2h2(unsigned u) {
    return *reinterpret_cast<__half2*>(&u);
}

// ---------------- GEMM1: x[N,128] @ W[128,32] -> f16 [N,32] ----------------
__global__ void gemm128x32(const float* __restrict__ x, const float* __restrict__ W,
                           unsigned short* __restrict__ outh, int n_nodes) {
    __shared__ float Ws[128 * 32];
    for (int i = threadIdx.x; i < 128 * 32; i += 256) Ws[i] = W[i];
    __syncthreads();
    const int fg = threadIdx.x & 7;
    const int nl = threadIdx.x >> 3;
    const int node = blockIdx.x * 32 + nl;
    if (node >= n_nodes) return;
    const float4* x4 = (const float4*)(x + (size_t)node * 128);
    const float4* Ws4 = (const float4*)Ws;
    float4 acc = make_float4(0.f, 0.f, 0.f, 0.f);
    for (int kk = 0; kk < 32; ++kk) {
        float4 xv = x4[kk];
        int k = kk * 4;
        float4 w0 = Ws4[(k + 0) * 8 + fg];
        float4 w1 = Ws4[(k + 1) * 8 + fg];
        float4 w2 = Ws4[(k + 2) * 8 + fg];
        float4 w3 = Ws4[(k + 3) * 8 + fg];
        acc.x += xv.x * w0.x + xv.y * w1.x + xv.z * w2.x + xv.w * w3.x;
        acc.y += xv.x * w0.y + xv.y * w1.y + xv.z * w2.y + xv.w * w3.y;
        acc.z += xv.x * w0.z + xv.y * w1.z + xv.z * w2.z + xv.w * w3.z;
        acc.w += xv.x * w0.w + xv.y * w1.w + xv.z * w2.w + xv.w * w3.w;
    }
    __half2 p0 = __floats2half2_rn(acc.x, acc.y);
    __half2 p1 = __floats2half2_rn(acc.z, acc.w);
    uint2 o = make_uint2(*reinterpret_cast<unsigned*>(&p0),
                         *reinterpret_cast<unsigned*>(&p1));
    ((uint2*)(outh + (size_t)node * 32))[fg] = o;
}

// ================= stage 0: cursor init (fixed-capacity buckets) =================
__global__ void init_cursor(int* __restrict__ cursor) {
    int t = blockIdx.x * blockDim.x + threadIdx.x;
    if (t < NB) cursor[t] = t * CAP;
}

// ====== stage 1: bucket multisplit, LDS-staged, hinted bucket lookup ======
__global__ __launch_bounds__(SBS) void bucket_scatter(
        const int* __restrict__ row, const int* __restrict__ col,
        const float* __restrict__ w, int* __restrict__ cursor,
        uint2* __restrict__ rec, int n_edges) {
    __shared__ uint2 srt[CHUNK];            // 64 KB
    __shared__ int hist[NB];
    __shared__ int lofs[NB + 1];
    __shared__ int lbase[NB];
    __shared__ int tsum[SBS];
    __shared__ unsigned short flr[CHUNK / 16];  // 1 KB bucket hints
    const int t = threadIdx.x;
    const int base = blockIdx.x * CHUNK;
    const int count = min(CHUNK, n_edges - base);

    if (t < NB) hist[t] = 0;
    __syncthreads();
    int rloc[CHUNK / SBS];                  // cache row[] between passes
    #pragma unroll
    for (int j = 0; j < CHUNK / SBS; ++j) {
        int i = t + j * SBS;
        int r = -1;
        if (i < count) { r = row[base + i]; atomicAdd(&hist[r >> 7], 1); }
        rloc[j] = r;
    }
    __syncthreads();
    int v = (t < NB) ? hist[t] : 0;
    tsum[t] = v;
    __syncthreads();
    for (int off = 1; off < SBS; off <<= 1) {
        int add = (t >= off) ? tsum[t - off] : 0;
        __syncthreads();
        tsum[t] += add;
        __syncthreads();
    }
    if (t < NB) lofs[t] = tsum[t] - v;
    if (t == SBS - 1) lofs[NB] = tsum[SBS - 1];
    __syncthreads();
    if (t < NB) {
        lbase[t] = v ? atomicAdd(&cursor[t], v) : 0;
        hist[t] = 0;
    }
    for (int q = t; q < CHUNK / 16; q += SBS) {
        int pos = q * 16;
        int lo = 0, hi = NB;
        while (hi - lo > 1) {
            int mid = (lo + hi) >> 1;
            if (lofs[mid] <= pos) lo = mid; else hi = mid;
        }
        flr[q] = (unsigned short)lo;
    }
    __syncthreads();
    #pragma unroll
    for (int j = 0; j < CHUNK / SBS; ++j) {
        int i = t + j * SBS;
        if (i < count) {
            int e = base + i;
            int r = rloc[j];
            int b = r >> 7;
            int pos = lofs[b] + atomicAdd(&hist[b], 1);
            srt[pos] = make_uint2(((unsigned)(r & 127) << 17) | (unsigned)col[e],
                                  __float_as_uint(w[e]));
        }
    }
    __syncthreads();
    for (int i = t; i < count; i += SBS) {
        uint2 vv = srt[i];
        int b = flr[i >> 4];
        while (lofs[b + 1] <= i) ++b;
        rec[lbase[b] + (i - lofs[b])] = vv;
    }
}

// ================= stage 2: compact-base scan over bucket counts =================
__global__ void scan_nb(const int* __restrict__ cursor, int* __restrict__ bbase) {
    __shared__ int s[1024];
    const int t = threadIdx.x;
    int v = (t < NB) ? (cursor[t] - t * CAP) : 0;
    s[t] = v;
    __syncthreads();
    for (int off = 1; off < 1024; off <<= 1) {
        int add = (t >= off) ? s[t - off] : 0;
        __syncthreads();
        s[t] += add;
        __syncthreads();
    }
    if (t < NB) bbase[t] = s[t] - v;
    if (t == NB - 1) bbase[NB] = s[t];
}

// ====== stage 3: per-bucket counting sort by (row_local, col_tile) -> CSR ======
// rec2[i] = (w_f16_no_sign:15) << 17 | col:17; each row's edges col-tile-ordered.
__global__ __launch_bounds__(512) void bucket_sort(
        const int* __restrict__ cursor, const int* __restrict__ bbase,
        const uint2* __restrict__ rec, unsigned* __restrict__ rec2,
        int* __restrict__ row_ptr, int n_nodes) {
    __shared__ unsigned srt[CAP];     // 20 KB
    __shared__ int hist[NKEYS];       // 8 KB
    __shared__ int lofs[NKEYS];       // 8 KB
    __shared__ int tsum[512];         // 2 KB
    const int t = threadIdx.x;
    const int b = blockIdx.x;
    const int sbase = b * CAP;
    const int cnt = cursor[b] - sbase;
    const int gbase = bbase[b];

    for (int i = t; i < NKEYS; i += 512) hist[i] = 0;
    __syncthreads();
    for (int i = t; i < cnt; i += 512) {
        unsigned rx = rec[sbase + i].x;
        int key = (rx >> 17) * CTILES + ((rx & 0x1FFFFu) >> 13);
        atomicAdd(&hist[key], 1);
    }
    __syncthreads();
    int vals[4];
    int s0 = 0;
    const int k4 = t * 4;
    #pragma unroll
    for (int j = 0; j < 4; ++j) { vals[j] = hist[k4 + j]; s0 += vals[j]; }
    tsum[t] = s0;
    __syncthreads();
    for (int off = 1; off < 512; off <<= 1) {
        int add = (t >= off) ? tsum[t - off] : 0;
        __syncthreads();
        tsum[t] += add;
        __syncthreads();
    }
    {
        int run = tsum[t] - s0;
        #pragma unroll
        for (int j = 0; j < 4; ++j) { lofs[k4 + j] = run; run += vals[j]; }
    }
    __syncthreads();
    if (t < RPB) {
        int gr = b * RPB + t;
        if (gr <= n_nodes) row_ptr[gr] = gbase + lofs[t * CTILES];
    }
    for (int i = t; i < NKEYS; i += 512) hist[i] = lofs[i];
    __syncthreads();
    for (int i = t; i < cnt; i += 512) {
        uint2 v = rec[sbase + i];
        int key = (v.x >> 17) * CTILES + ((v.x & 0x1FFFFu) >> 13);
        int pos = atomicAdd(&hist[key], 1);
        float wf = __uint_as_float(v.y);
        __half hw = __float2half_rn(wf);
        unsigned wb = ((unsigned)*reinterpret_cast<unsigned short*>(&hw)) & 0x7FFFu;
        srt[pos] = (wb << 17) | (v.x & 0x1FFFFu);
    }
    __syncthreads();
    for (int i = t; i < cnt; i += 512)
        rec2[gbase + i] = srt[i];
}

// ====== fused SPMM: act = ELU(A.h + b); then project @Wn -> f16, or pool. ======
// 4 lanes/node (uint4 = 8 f16 feats each), 64 nodes/block, packed-f16 FMA.
__global__ __launch_bounds__(256) void spmm_fused(
        const int* __restrict__ rp, const unsigned* __restrict__ rec2,
        const unsigned short* __restrict__ h_in, const float* __restrict__ bias,
        const float* __restrict__ Wn,          // 32x32 or nullptr (last layer)
        unsigned short* __restrict__ h_out,    // f16 out if Wn != nullptr
        const int* __restrict__ seg,           // used if Wn == nullptr
        float* __restrict__ G,                 // pooled out if Wn == nullptr
        int n_nodes) {
    __shared__ float Ws[32 * 32];
    __shared__ float vt[SPB][33];
    const int t = threadIdx.x;
    if (Wn) for (int i = t; i < 1024; i += 256) Ws[i] = Wn[i];
    const int fl = t & 3;
    const int nl = t >> 2;
    const int node = blockIdx.x * SPB + nl;
    const bool valid = node < n_nodes;
    const int s = valid ? rp[node] : 0;
    const int e = valid ? rp[node + 1] : 0;
    const uint4* h4 = (const uint4*)h_in;     // row = 4 uint4 (32 f16)
    __half2 a0 = u2h2(0), a1 = u2h2(0), a2 = u2h2(0), a3 = u2h2(0);
    int i = s;
    for (; i < e && (i & 3); ++i) {
        unsigned p0 = rec2[i];
        uint4 g0 = h4[(size_t)(p0 & 0x1FFFF) * 4 + fl];
        unsigned wu = p0 >> 17; wu |= wu << 16;
        __half2 w2 = u2h2(wu);
        a0 = __hfma2(w2, u2h2(g0.x), a0);
        a1 = __hfma2(w2, u2h2(g0.y), a1);
        a2 = __hfma2(w2, u2h2(g0.z), a2);
        a3 = __hfma2(w2, u2h2(g0.w), a3);
    }
    for (; i + 8 <= e; i += 8) {
        uint4 pa = *(const uint4*)(rec2 + i);
        uint4 pb = *(const uint4*)(rec2 + i + 4);
        unsigned p[8] = {pa.x, pa.y, pa.z, pa.w, pb.x, pb.y, pb.z, pb.w};
        uint4 g[8];
        #pragma unroll
        for (int j = 0; j < 8; ++j) g[j] = h4[(size_t)(p[j] & 0x1FFFF) * 4 + fl];
        #pragma unroll
        for (int j = 0; j < 8; ++j) {
            unsigned wu = p[j] >> 17; wu |= wu << 16;
            __half2 w2 = u2h2(wu);
            a0 = __hfma2(w2, u2h2(g[j].x), a0);
            a1 = __hfma2(w2, u2h2(g[j].y), a1);
            a2 = __hfma2(w2, u2h2(g[j].z), a2);
            a3 = __hfma2(w2, u2h2(g[j].w), a3);
        }
    }
    for (; i < e; ++i) {
        unsigned p0 = rec2[i];
        uint4 g0 = h4[(size_t)(p0 & 0x1FFFF) * 4 + fl];
        unsigned wu = p0 >> 17; wu |= wu << 16;
        __half2 w2 = u2h2(wu);
        a0 = __hfma2(w2, u2h2(g0.x), a0);
        a1 = __hfma2(w2, u2h2(g0.y), a1);
        a2 = __hfma2(w2, u2h2(g0.z), a2);
        a3 = __hfma2(w2, u2h2(g0.w), a3);
    }
    // bias + ELU in fp32
    float acc[8];
    acc[0] = __low2float(a0); acc[1] = __high2float(a0);
    acc[2] = __low2float(a1); acc[3] = __high2float(a1);
    acc[4] = __low2float(a2); acc[5] = __high2float(a2);
    acc[6] = __low2float(a3); acc[7] = __high2float(a3);
    float4 bv0 = ((const float4*)bias)[fl * 2];
    float4 bv1 = ((const float4*)bias)[fl * 2 + 1];
    acc[0] += bv0.x; acc[1] += bv0.y; acc[2] += bv0.z; acc[3] += bv0.w;
    acc[4] += bv1.x; acc[5] += bv1.y; acc[6] += bv1.z; acc[7] += bv1.w;
    #pragma unroll
    for (int j = 0; j < 8; ++j)
        acc[j] = acc[j] > 0.f ? acc[j] : (expf(acc[j]) - 1.f);
    // stage act in LDS
    {
        float* vr = &vt[nl][fl * 8];
        #pragma unroll
        for (int j = 0; j < 8; ++j) vr[j] = acc[j];
    }
    __syncthreads();

    if (Wn) {
        // project @ Wn, emit f16
        const float4* Ws4 = (const float4*)Ws;
        const float* vrow = vt[nl];
        float o[8] = {0.f, 0.f, 0.f, 0.f, 0.f, 0.f, 0.f, 0.f};
        #pragma unroll 8
        for (int k = 0; k < 32; ++k) {
            float vk = vrow[k];
            float4 w0 = Ws4[k * 8 + fl * 2];
            float4 w1 = Ws4[k * 8 + fl * 2 + 1];
            o[0] += vk * w0.x; o[1] += vk * w0.y; o[2] += vk * w0.z; o[3] += vk * w0.w;
            o[4] += vk * w1.x; o[5] += vk * w1.y; o[6] += vk * w1.z; o[7] += vk * w1.w;
        }
        if (valid) {
            __half2 q0 = __floats2half2_rn(o[0], o[1]);
            __half2 q1 = __floats2half2_rn(o[2], o[3]);
            __half2 q2 = __floats2half2_rn(o[4], o[5]);
            __half2 q3 = __floats2half2_rn(o[6], o[7]);
            uint4 ob = make_uint4(*reinterpret_cast<unsigned*>(&q0),
                                  *reinterpret_cast<unsigned*>(&q1),
                                  *reinterpret_cast<unsigned*>(&q2),
                                  *reinterpret_cast<unsigned*>(&q3));
            ((uint4*)h_out)[(size_t)node * 4 + fl] = ob;
        }
    } else {
        // pool: 32 feat lanes x 8 subs, run-accumulate sorted seg over 8 nodes each
        const int f = t & 31;
        const int sub = t >> 5;
        float run = 0.f;
        int cur = -1;
        #pragma unroll
        for (int q = 0; q < 8; ++q) {
            int nloc = sub * 8 + q;
            int node2 = blockIdx.x * SPB + nloc;
            if (node2 >= n_nodes) break;
            int sg = seg[node2];
            if (sg != cur) {
                if (cur >= 0) atomicAdd(&G[(size_t)cur * 32 + f], run);
                cur = sg;
                run = 0.f;
            }
            run += vt[nloc][f];
        }
        if (cur >= 0) atomicAdd(&G[(size_t)cur * 32 + f], run);
    }
}

// ================= MLP head =================
__global__ void head_mlp(const float* __restrict__ g,
                         const float* __restrict__ Wd1, const float* __restrict__ bd1,
                         const float* __restrict__ Wd2, const float* __restrict__ bd2,
                         const float* __restrict__ Wd3, const float* __restrict__ bd3,
                         float* __restrict__ out) {
    __shared__ float gr[32];
    __shared__ float s1[64];
    __shared__ float s2[32];
    const int gid = blockIdx.x;
    const int t = threadIdx.x;
    if (t < 32) gr[t] = g[(size_t)gid * 32 + t];
    __syncthreads();
    float a = bd1[t];
    for (int k = 0; k < 32; ++k) a += gr[k] * Wd1[k * 64 + t];
    s1[t] = fmaxf(a, 0.f);
    __syncthreads();
    if (t < 32) {
        float a2 = bd2[t];
        for (int k = 0; k < 64; ++k) a2 += s1[k] * Wd2[k * 32 + t];
        s2[t] = fmaxf(a2, 0.f);
    }
    __syncthreads();
    if (t == 0) {
        float a3 = bd3[0];
        for (int k = 0; k < 32; ++k) a3 += s2[k] * Wd3[k];
        out[gid] = 1.f / (1.f + expf(-a3));
    }
}

extern "C" void kernel_launch(void* const* d_in, const int* in_sizes, int n_in,
                              void* d_out, int out_size, void* d_ws, size_t ws_size,
                              hipStream_t stream) {
    const float* x   = (const float*)d_in[0];
    const int*   ei  = (const int*)d_in[1];
    const float* ew  = (const float*)d_in[2];
    const int*   seg = (const int*)d_in[3];
    const float* W1  = (const float*)d_in[4];
    const float* b1  = (const float*)d_in[5];
    const float* W2  = (const float*)d_in[6];
    const float* b2  = (const float*)d_in[7];
    const float* W3  = (const float*)d_in[8];
    const float* b3  = (const float*)d_in[9];
    const float* Wd1 = (const float*)d_in[10];
    const float* bd1 = (const float*)d_in[11];
    const float* Wd2 = (const float*)d_in[12];
    const float* bd2 = (const float*)d_in[13];
    const float* Wd3 = (const float*)d_in[14];
    const float* bd3 = (const float*)d_in[15];
    float* out = (float*)d_out;

    const int* rowp = ei;
    const int* colp = ei + N_EDGES;

    const size_t NF  = (size_t)N_NODES * F_HID;
    const size_t REC_BYTES = (size_t)NB * CAP * sizeof(uint2);  // 32.03 MB

    // region A: rec (32 MB) during build; hA (6.4) + hB (6.4) f16 overlay after
    char*  wsb     = (char*)d_ws;
    uint2* rec     = (uint2*)wsb;
    unsigned short* hA = (unsigned short*)wsb;                  // f16 [N,32]
    unsigned short* hB = (unsigned short*)(wsb + NF * 2);       // f16 [N,32]
    unsigned* rec2 = (unsigned*)(wsb + REC_BYTES);              // [E] 4 B records
    int*   cursor  = (int*)(rec2 + N_EDGES);                    // [NB]
    int*   bbase   = cursor + NB;                               // [NB+1]
    int*   row_ptr = bbase + NB + 1;                            // [N+1]
    float* G       = (float*)(row_ptr + N_NODES + 1);           // [512,32]

    const int gemm_grid = (N_NODES + 31) / 32;    // 3125
    const int spmm_grid = (N_NODES + SPB - 1) / SPB;  // 1563

    // ---- CSR build (once per call) ----
    init_cursor<<<(NB + 255) / 256, 256, 0, stream>>>(cursor);
    bucket_scatter<<<NCHUNK, SBS, 0, stream>>>(rowp, colp, ew, cursor, rec, N_EDGES);
    scan_nb<<<1, 1024, 0, stream>>>(cursor, bbase);
    bucket_sort<<<NB, 512, 0, stream>>>(cursor, bbase, rec, rec2, row_ptr, N_NODES);
    hipMemsetAsync(G, 0, (size_t)N_GRAPHS * F_HID * sizeof(float), stream);

    // ---- layer 1: project x@W1 -> hA; fused spmm(+b1,ELU) @W2 -> hB ----
    gemm128x32<<<gemm_grid, 256, 0, stream>>>(x, W1, hA, N_NODES);
    spmm_fused<<<spmm_grid, 256, 0, stream>>>(row_ptr, rec2, hA, b1, W2, hB, nullptr, nullptr, N_NODES);

    // ---- layer 2: fused spmm(+b2,ELU) @W3 -> hA ----
    spmm_fused<<<spmm_grid, 256, 0, stream>>>(row_ptr, rec2, hB, b2, W3, hA, nullptr, nullptr, N_NODES);

    // ---- layer 3: fused spmm(+b3,ELU) + pool -> G ----
    spmm_fused<<<spmm_grid, 256, 0, stream>>>(row_ptr, rec2, hA, b3, nullptr, nullptr, seg, G, N_NODES);

    // ---- head ----
    head_mlp<<<N_GRAPHS, 64, 0, stream>>>(G, Wd1, bd1, Wd2, bd2, Wd3, bd3, out);
}